// Round 2
// 840.414 us; speedup vs baseline: 1.3896x; 1.3896x over previous
//
#include <hip/hip_runtime.h>
#include <hip/hip_bf16.h>
#include <stdint.h>

#define Bx  2
#define Tx  2048
#define Dx  1024
#define Hx  16
#define DKx 64

typedef unsigned short u16;
typedef short bf16x8 __attribute__((ext_vector_type(8)));
typedef float f32x4 __attribute__((ext_vector_type(4)));

#define QKVE ((size_t)Bx * Tx * Dx)   /* 4,194,304 = 2^22 elems */
#define WEL  ((size_t)Dx * Dx)        /* 1,048,576 = 2^20 elems */

static __device__ __forceinline__ u16 f32_to_bf16(float f) {
  union { float f; unsigned u; } v; v.f = f;
  unsigned r = v.u + 0x7fffu + ((v.u >> 16) & 1u);
  return (u16)(r >> 16);
}

// ---- async 16B global -> LDS (direct-to-shared DMA) ----
static __device__ __forceinline__ void gld_lds16(const u16* g, u16* l) {
  __builtin_amdgcn_global_load_lds(
      (__attribute__((address_space(1))) const unsigned int*)g,
      (__attribute__((address_space(3))) unsigned int*)l, 16, 0, 0);
}

// bf16 tile stager via global_load_lds. LDS layout is linear r*COLS+c,
// byte offset of chunk c is c*16 => matches HW's wave-uniform-base + lane*16.
template <int ROWS, int COLS>
static __device__ __forceinline__ void stage_lds_b16(const u16* __restrict__ g,
                                                     int gstride, u16* lds) {
  constexpr int CPR = COLS / 8;          // 16B chunks per row
  constexpr int TOTAL = ROWS * CPR;
  const int lane = threadIdx.x & 63;
  const int wb = threadIdx.x & ~63;      // wave base (uniform within wave)
#pragma unroll
  for (int base = 0; base < TOTAL; base += 256) {
    const int c = base + wb + lane;
    const int r = c / CPR;
    const int cc = c % CPR;
    gld_lds16(g + (size_t)r * gstride + cc * 8, lds + (size_t)(base + wb) * 8);
  }
}

// f32 tile stager (convert to bf16 in regs) -- only for Wo in the final GEMM.
template <int ROWS, int COLS>
static __device__ __forceinline__ void stage_tile_f32(const float* __restrict__ g,
                                                      int gstride, u16* lds) {
  constexpr int CPR = COLS / 4;          // float4 chunks per row
  constexpr int TOTAL = ROWS * CPR;
  const int tid = threadIdx.x;
#pragma unroll
  for (int base = 0; base < TOTAL; base += 256) {
    int c = base + tid;
    int r = c / CPR;
    int cc = c % CPR;
    float4 v = *(const float4*)(g + (size_t)r * gstride + cc * 4);
    ushort4 p;
    p.x = f32_to_bf16(v.x);
    p.y = f32_to_bf16(v.y);
    p.z = f32_to_bf16(v.z);
    p.w = f32_to_bf16(v.w);
    *(ushort4*)&lds[(size_t)r * COLS + cc * 4] = p;
  }
}

// One-shot f32->bf16 convert of q,k,v,Wq,Wk,Wv into scratch (attnW region,
// dead until attn_kernel). Removes per-k-step conversion VALU from all GEMMs.
__global__ __launch_bounds__(256) void cvt_kernel(
    const float* __restrict__ q, const float* __restrict__ k,
    const float* __restrict__ v, const float* __restrict__ wq,
    const float* __restrict__ wk, const float* __restrict__ wv,
    u16* __restrict__ dst) {
  const size_t total4 = (3 * QKVE + 3 * WEL) / 4;
  for (size_t i = (size_t)blockIdx.x * blockDim.x + threadIdx.x; i < total4;
       i += (size_t)gridDim.x * blockDim.x) {
    size_t e = i * 4;
    const float* src;
    size_t off;
    if (e < 3 * QKVE) {
      int w = (int)(e >> 22);
      src = (w == 0) ? q : (w == 1) ? k : v;
      off = e - ((size_t)w << 22);
    } else {
      size_t e2 = e - 3 * QKVE;
      int w = (int)(e2 >> 20);
      src = (w == 0) ? wq : (w == 1) ? wk : wv;
      off = e2 - ((size_t)w << 20);
    }
    float4 x = *(const float4*)(src + off);
    ushort4 p;
    p.x = f32_to_bf16(x.x);
    p.y = f32_to_bf16(x.y);
    p.z = f32_to_bf16(x.z);
    p.w = f32_to_bf16(x.w);
    *(ushort4*)(dst + e) = p;
  }
}

// Fused Q/K/V projection. grid = (8, 32, 3): z=0 -> Qp, z=1 -> Kp (split-head
// (B,H,T,DK)); z=2 -> Vtp ((B,H,DK,T) transposed). All-bf16, m97-style
// global_load_lds staging, 128x128 tile, 4 waves * 4x4 16x16x32 MFMAs.
__global__ __launch_bounds__(256) void gemm_qkv(
    const u16* __restrict__ cvt, u16* __restrict__ Qp,
    u16* __restrict__ Kp, u16* __restrict__ Vtp) {
  __shared__ u16 As[128 * 64];
  __shared__ u16 Bs[128 * 64];
  const int z = blockIdx.z;
  const u16* A = cvt + (size_t)z * QKVE;
  const u16* W = cvt + 3 * QKVE + (size_t)z * WEL;
  u16* dst = (z == 0) ? Qp : (z == 1) ? Kp : Vtp;
  const int K = Dx;
  const int tid = threadIdx.x;
  const int lane = tid & 63;
  const int l15 = lane & 15;
  const int quad = lane >> 4;
  const int wave = tid >> 6;
  const int m0 = blockIdx.y * 128;
  const int n0 = blockIdx.x * 128;
  const int wr = (wave >> 1) * 64;
  const int wc = (wave & 1) * 64;

  f32x4 acc[4][4];
#pragma unroll
  for (int i = 0; i < 4; i++)
#pragma unroll
    for (int j = 0; j < 4; j++) acc[i][j] = f32x4{0.f, 0.f, 0.f, 0.f};

  for (int k0 = 0; k0 < K; k0 += 64) {
    stage_lds_b16<128, 64>(A + (size_t)m0 * K + k0, K, As);
    stage_lds_b16<128, 64>(W + (size_t)n0 * K + k0, K, Bs);
    __syncthreads();
#pragma unroll
    for (int kk = 0; kk < 2; kk++) {
      bf16x8 af[4], bfv[4];
#pragma unroll
      for (int i = 0; i < 4; i++)
        af[i] = *(const bf16x8*)&As[(wr + i * 16 + l15) * 64 + kk * 32 + quad * 8];
#pragma unroll
      for (int j = 0; j < 4; j++)
        bfv[j] = *(const bf16x8*)&Bs[(wc + j * 16 + l15) * 64 + kk * 32 + quad * 8];
#pragma unroll
      for (int i = 0; i < 4; i++)
#pragma unroll
        for (int j = 0; j < 4; j++)
          acc[i][j] = __builtin_amdgcn_mfma_f32_16x16x32_bf16(af[i], bfv[j],
                                                              acc[i][j], 0, 0, 0);
    }
    __syncthreads();
  }

#pragma unroll
  for (int i = 0; i < 4; i++)
#pragma unroll
    for (int j = 0; j < 4; j++)
#pragma unroll
      for (int r = 0; r < 4; r++) {
        int row = m0 + wr + i * 16 + quad * 4 + r;  // token index
        int col = n0 + wc + j * 16 + l15;           // feature index
        float fv = acc[i][j][r];
        int b = row >> 11, t = row & 2047;
        int h = col >> 6, dk = col & 63;
        if (z != 2) {
          dst[(((size_t)(b * Hx + h) * Tx) + t) * DKx + dk] = f32_to_bf16(fv);
        } else {
          dst[(((size_t)(b * Hx + h) * DKx) + dk) * Tx + t] = f32_to_bf16(fv);
        }
      }
}

// Final output GEMM: A = comb (bf16 ws) via global_load_lds, B = Wo (f32,
// converted in-kernel), C = f32 row-major, nontemporal (never re-read).
__global__ __launch_bounds__(256) void gemm_out(
    const u16* __restrict__ Acomb, const float* __restrict__ Wo,
    float* __restrict__ out) {
  __shared__ u16 As[128 * 64];
  __shared__ u16 Bs[128 * 64];
  const int K = Dx, N = Dx;
  const int tid = threadIdx.x;
  const int lane = tid & 63;
  const int l15 = lane & 15;
  const int quad = lane >> 4;
  const int wave = tid >> 6;
  const int m0 = blockIdx.y * 128;
  const int n0 = blockIdx.x * 128;
  const int wr = (wave >> 1) * 64;
  const int wc = (wave & 1) * 64;

  f32x4 acc[4][4];
#pragma unroll
  for (int i = 0; i < 4; i++)
#pragma unroll
    for (int j = 0; j < 4; j++) acc[i][j] = f32x4{0.f, 0.f, 0.f, 0.f};

  for (int k0 = 0; k0 < K; k0 += 64) {
    stage_lds_b16<128, 64>(Acomb + (size_t)m0 * K + k0, K, As);
    stage_tile_f32<128, 64>(Wo + (size_t)n0 * K + k0, K, Bs);
    __syncthreads();
#pragma unroll
    for (int kk = 0; kk < 2; kk++) {
      bf16x8 af[4], bfv[4];
#pragma unroll
      for (int i = 0; i < 4; i++)
        af[i] = *(const bf16x8*)&As[(wr + i * 16 + l15) * 64 + kk * 32 + quad * 8];
#pragma unroll
      for (int j = 0; j < 4; j++)
        bfv[j] = *(const bf16x8*)&Bs[(wc + j * 16 + l15) * 64 + kk * 32 + quad * 8];
#pragma unroll
      for (int i = 0; i < 4; i++)
#pragma unroll
        for (int j = 0; j < 4; j++)
          acc[i][j] = __builtin_amdgcn_mfma_f32_16x16x32_bf16(af[i], bfv[j],
                                                              acc[i][j], 0, 0, 0);
    }
    __syncthreads();
  }

#pragma unroll
  for (int i = 0; i < 4; i++)
#pragma unroll
    for (int j = 0; j < 4; j++)
#pragma unroll
      for (int r = 0; r < 4; r++) {
        int row = m0 + wr + i * 16 + quad * 4 + r;
        int col = n0 + wc + j * 16 + l15;
        __builtin_nontemporal_store(acc[i][j][r], &out[(size_t)row * N + col]);
      }
}

// Attention: grid.x = T/64 (q blocks of 64), grid.y = B*H.
// 4 waves; each wave owns 16 q rows. Pass A: online softmax (m,l).
// Pass B: recompute S, write P (f32 attn weights, nontemporal) + O = P*V.
__global__ __launch_bounds__(256) void attn_kernel(
    const u16* __restrict__ Q,    // (B,H,T,DK) bf16 ws
    const u16* __restrict__ Kt,   // (B,H,T,DK) bf16 ws
    const u16* __restrict__ Vt,   // (B,H,DK,T) bf16 ws
    float* __restrict__ attnW,    // (B,H,T,T)  FLOAT32 out
    u16* __restrict__ comb) {     // (B,T,D)    bf16 ws
  __shared__ u16 Ks[128 * 64];
  __shared__ u16 Vs[64 * 128];
  __shared__ u16 Ps[4][16 * 128];

  const int tid = threadIdx.x, lane = tid & 63, wave = tid >> 6;
  const int l15 = lane & 15, quad = lane >> 4;
  const int bh = blockIdx.y;
  const int b = bh >> 4, h = bh & 15;
  const int q0 = blockIdx.x * 64;
  const u16* Qbh = Q + (size_t)bh * Tx * DKx;
  const u16* Kbh = Kt + (size_t)bh * Tx * DKx;
  const u16* Vbh = Vt + (size_t)bh * DKx * Tx;
  float* Wbh = attnW + (size_t)bh * Tx * Tx;

  // Q fragments for this wave's 16 rows (A-operand layout: m=l15, k=quad*8+j)
  bf16x8 qf[2];
  {
    const u16* qrow = Qbh + (size_t)(q0 + wave * 16 + l15) * DKx;
    qf[0] = *(const bf16x8*)(qrow + quad * 8);
    qf[1] = *(const bf16x8*)(qrow + 32 + quad * 8);
  }
  const int myrow_base = q0 + wave * 16;
  float m_r[4], l_r[4];
#pragma unroll
  for (int r = 0; r < 4; r++) { m_r[r] = -1e30f; l_r[r] = 0.0f; }

  const int ktmax = (q0 + 63) >> 7;  // inclusive: tiles with any visible col
  const float scale = 0.125f;        // 1/sqrt(64)

  // ---- Pass A: running max / denom ----
  for (int kt = 0; kt <= ktmax; kt++) {
    stage_lds_b16<128, 64>(Kbh + (size_t)kt * 128 * DKx, DKx, Ks);
    __syncthreads();
    f32x4 s[8];
#pragma unroll
    for (int j = 0; j < 8; j++) s[j] = f32x4{0.f, 0.f, 0.f, 0.f};
#pragma unroll
    for (int kk = 0; kk < 2; kk++)
#pragma unroll
      for (int j = 0; j < 8; j++) {
        bf16x8 bfr = *(const bf16x8*)&Ks[(j * 16 + l15) * 64 + kk * 32 + quad * 8];
        s[j] = __builtin_amdgcn_mfma_f32_16x16x32_bf16(qf[kk], bfr, s[j], 0, 0, 0);
      }
#pragma unroll
    for (int r = 0; r < 4; r++) {
      int row = myrow_base + quad * 4 + r;
      float vals[8];
      float mx = -1e30f;
#pragma unroll
      for (int j = 0; j < 8; j++) {
        int col = kt * 128 + j * 16 + l15;
        float v = (col <= row) ? s[j][r] * scale : -1e30f;
        vals[j] = v;
        mx = fmaxf(mx, v);
      }
#pragma unroll
      for (int off = 1; off < 16; off <<= 1) mx = fmaxf(mx, __shfl_xor(mx, off));
      float mnew = fmaxf(m_r[r], mx);
      float sum = 0.0f;
#pragma unroll
      for (int j = 0; j < 8; j++) sum += __expf(vals[j] - mnew);
#pragma unroll
      for (int off = 1; off < 16; off <<= 1) sum += __shfl_xor(sum, off);
      l_r[r] = l_r[r] * __expf(m_r[r] - mnew) + sum;
      m_r[r] = mnew;
    }
    __syncthreads();
  }

  float il[4];
#pragma unroll
  for (int r = 0; r < 4; r++) il[r] = 1.0f / l_r[r];

  f32x4 o[4];
#pragma unroll
  for (int j = 0; j < 4; j++) o[j] = f32x4{0.f, 0.f, 0.f, 0.f};

  u16* Pw = Ps[wave];

  // ---- Pass B: P write (f32) + PV accumulate ----
  for (int kt = 0; kt < Tx / 128; kt++) {
    if (kt <= ktmax) {
      stage_lds_b16<128, 64>(Kbh + (size_t)kt * 128 * DKx, DKx, Ks);
      stage_lds_b16<64, 128>(Vbh + (size_t)kt * 128, Tx, Vs);
      __syncthreads();
      f32x4 s[8];
#pragma unroll
      for (int j = 0; j < 8; j++) s[j] = f32x4{0.f, 0.f, 0.f, 0.f};
#pragma unroll
      for (int kk = 0; kk < 2; kk++)
#pragma unroll
        for (int j = 0; j < 8; j++) {
          bf16x8 bfr = *(const bf16x8*)&Ks[(j * 16 + l15) * 64 + kk * 32 + quad * 8];
          s[j] = __builtin_amdgcn_mfma_f32_16x16x32_bf16(qf[kk], bfr, s[j], 0, 0, 0);
        }
      // P = exp(s - m)/l: f32 -> global (nontemporal; 537 MB stream),
      // bf16 -> LDS (A-layout transform for the PV MFMA)
#pragma unroll
      for (int j = 0; j < 8; j++)
#pragma unroll
        for (int r = 0; r < 4; r++) {
          int row = myrow_base + quad * 4 + r;
          int col = kt * 128 + j * 16 + l15;
          float p = (col <= row) ? __expf(s[j][r] * scale - m_r[r]) * il[r] : 0.0f;
          Pw[(quad * 4 + r) * 128 + j * 16 + l15] = f32_to_bf16(p);
          __builtin_nontemporal_store(p, &Wbh[(size_t)row * Tx + col]);
        }
      // O += P * V
#pragma unroll
      for (int kk = 0; kk < 4; kk++) {
        bf16x8 af = *(const bf16x8*)&Pw[l15 * 128 + kk * 32 + quad * 8];
#pragma unroll
        for (int j = 0; j < 4; j++) {
          bf16x8 bfr = *(const bf16x8*)&Vs[(j * 16 + l15) * 128 + kk * 32 + quad * 8];
          o[j] = __builtin_amdgcn_mfma_f32_16x16x32_bf16(af, bfr, o[j], 0, 0, 0);
        }
      }
      __syncthreads();
    } else {
      // fully masked tile: f32 zeros (16 rows x 128 cols), ext-vector
      // nontemporal stores (HIP float4 class is rejected by the builtin)
      f32x4 z = {0.f, 0.f, 0.f, 0.f};
#pragma unroll
      for (int i = 0; i < 8; i++) {
        int c = i * 64 + lane;          // 0..511
        int pr = c >> 5, pc = c & 31;   // row 0..15, float4 chunk 0..31
        __builtin_nontemporal_store(
            z, (f32x4*)&Wbh[(size_t)(myrow_base + pr) * Tx + kt * 128 + pc * 4]);
      }
    }
  }

  // write O into combined (B,T,D) bf16 ws layout
#pragma unroll
  for (int j = 0; j < 4; j++)
#pragma unroll
    for (int r = 0; r < 4; r++) {
      int row = myrow_base + quad * 4 + r;   // t
      int dk = j * 16 + l15;
      comb[((size_t)b * Tx + row) * Dx + h * 64 + dk] = f32_to_bf16(o[j][r]);
    }
}

extern "C" void kernel_launch(void* const* d_in, const int* in_sizes, int n_in,
                              void* d_out, int out_size, void* d_ws, size_t ws_size,
                              hipStream_t stream) {
  // Inputs AND outputs are FLOAT32 per the reference.
  const float* q  = (const float*)d_in[0];
  const float* k  = (const float*)d_in[1];
  const float* v  = (const float*)d_in[2];
  // d_in[3] = causal mask -- deterministic triu(k=1), recomputed in-kernel
  const float* Wq = (const float*)d_in[4];
  const float* Wk = (const float*)d_in[5];
  const float* Wv = (const float*)d_in[6];
  const float* Wo = (const float*)d_in[7];

  float* out  = (float*)d_out;                    // (B,T,D) f32
  float* attn = out + QKVE;                       // (B,H,T,T) f32

  u16* ws = (u16*)d_ws;
  const size_t QKV = QKVE;                        // 4,194,304 elems
  u16* Qp   = ws;
  u16* Kp   = ws + QKV;
  u16* Vtp  = ws + 2 * QKV;
  u16* comb = ws + 3 * QKV;

  // bf16 staging scratch lives in the attnW output region: it is dead until
  // attn_kernel overwrites every element of attnW (ws footprint unchanged).
  u16* cvt = (u16*)attn;  // 3*QKVE + 3*WEL u16 = 33.6 MB << 537 MB

  dim3 blk(256);
  cvt_kernel<<<dim3(1024), blk, 0, stream>>>(q, k, v, Wq, Wk, Wv, cvt);

  dim3 g1(Dx / 128, (Bx * Tx) / 128, 3);  // (8, 32, 3) = 768 blocks
  gemm_qkv<<<g1, blk, 0, stream>>>(cvt, Qp, Kp, Vtp);

  dim3 g2(Tx / 64, Bx * Hx);  // (32, 32)
  attn_kernel<<<g2, blk, 0, stream>>>(Qp, Kp, Vtp, attn, comb);

  dim3 g3(Dx / 128, (Bx * Tx) / 128);  // (8, 32)
  gemm_out<<<g3, blk, 0, stream>>>(comb, Wo, out);
}

// Round 4
// 793.709 us; speedup vs baseline: 1.4714x; 1.0588x over previous
//
#include <hip/hip_runtime.h>
#include <hip/hip_bf16.h>
#include <stdint.h>

#define Bx  2
#define Tx  2048
#define Dx  1024
#define Hx  16
#define DKx 64

typedef unsigned short u16;
typedef short bf16x8 __attribute__((ext_vector_type(8)));
typedef float f32x4 __attribute__((ext_vector_type(4)));

#define QKVE ((size_t)Bx * Tx * Dx)   /* 4,194,304 = 2^22 elems */
#define WEL  ((size_t)Dx * Dx)        /* 1,048,576 = 2^20 elems */

static __device__ __forceinline__ u16 f32_to_bf16(float f) {
  union { float f; unsigned u; } v; v.f = f;
  unsigned r = v.u + 0x7fffu + ((v.u >> 16) & 1u);
  return (u16)(r >> 16);
}

// ---- async 16B global -> LDS (direct-to-shared DMA) ----
static __device__ __forceinline__ void gld_lds16(const u16* g, u16* l) {
  __builtin_amdgcn_global_load_lds(
      (__attribute__((address_space(1))) const unsigned int*)g,
      (__attribute__((address_space(3))) unsigned int*)l, 16, 0, 0);
}

// bf16 tile stager via global_load_lds. LDS layout is linear r*COLS+c
// (dest chunk = base+wb+lane, HW lands it at wave-base + lane*16).
// SWZ: pre-swizzle the per-lane GLOBAL source chunk (slot ^= row&(CPR-1))
// so that readers applying idx ^= ((row&(CPR-1))<<3) see correct data
// with bank-conflict-free access (rule #21: both-sides-or-neither).
template <int ROWS, int COLS, bool SWZ>
static __device__ __forceinline__ void stage_lds_b16(const u16* __restrict__ g,
                                                     int gstride, u16* lds) {
  constexpr int CPR = COLS / 8;          // 16B chunks per row
  constexpr int TOTAL = ROWS * CPR;
  const int lane = threadIdx.x & 63;
  const int wb = threadIdx.x & ~63;      // wave base (uniform within wave)
#pragma unroll
  for (int base = 0; base < TOTAL; base += 256) {
    const int c = base + wb + lane;
    const int r = c / CPR;
    int sl = c % CPR;
    if (SWZ) sl ^= (r & (CPR - 1));
    gld_lds16(g + (size_t)r * gstride + sl * 8, lds + (size_t)(base + wb) * 8);
  }
}

// f32 tile stager (convert to bf16 in regs) -- only for Wo in the final GEMM.
template <int ROWS, int COLS>
static __device__ __forceinline__ void stage_tile_f32(const float* __restrict__ g,
                                                      int gstride, u16* lds) {
  constexpr int CPR = COLS / 4;          // float4 chunks per row
  constexpr int TOTAL = ROWS * CPR;
  const int tid = threadIdx.x;
#pragma unroll
  for (int base = 0; base < TOTAL; base += 256) {
    int c = base + tid;
    int r = c / CPR;
    int cc = c % CPR;
    float4 v = *(const float4*)(g + (size_t)r * gstride + cc * 4);
    ushort4 p;
    p.x = f32_to_bf16(v.x);
    p.y = f32_to_bf16(v.y);
    p.z = f32_to_bf16(v.z);
    p.w = f32_to_bf16(v.w);
    *(ushort4*)&lds[(size_t)r * COLS + cc * 4] = p;
  }
}

// One-shot f32->bf16 convert of q,k,v,Wq,Wk,Wv into scratch (attnW region,
// dead until attn_kernel). Removes per-k-step conversion VALU from all GEMMs.
__global__ __launch_bounds__(256) void cvt_kernel(
    const float* __restrict__ q, const float* __restrict__ k,
    const float* __restrict__ v, const float* __restrict__ wq,
    const float* __restrict__ wk, const float* __restrict__ wv,
    u16* __restrict__ dst) {
  const size_t total4 = (3 * QKVE + 3 * WEL) / 4;
  for (size_t i = (size_t)blockIdx.x * blockDim.x + threadIdx.x; i < total4;
       i += (size_t)gridDim.x * blockDim.x) {
    size_t e = i * 4;
    const float* src;
    size_t off;
    if (e < 3 * QKVE) {
      int w = (int)(e >> 22);
      src = (w == 0) ? q : (w == 1) ? k : v;
      off = e - ((size_t)w << 22);
    } else {
      size_t e2 = e - 3 * QKVE;
      int w = (int)(e2 >> 20);
      src = (w == 0) ? wq : (w == 1) ? wk : wv;
      off = e2 - ((size_t)w << 20);
    }
    float4 x = *(const float4*)(src + off);
    ushort4 p;
    p.x = f32_to_bf16(x.x);
    p.y = f32_to_bf16(x.y);
    p.z = f32_to_bf16(x.z);
    p.w = f32_to_bf16(x.w);
    *(ushort4*)(dst + e) = p;
  }
}

// Fused Q/K/V projection. grid = (8, 32, 3): z=0 -> Qp, z=1 -> Kp (split-head
// (B,H,T,DK)); z=2 -> Vtp ((B,H,DK,T) transposed). All-bf16, m97-style
// global_load_lds staging, 128x128 tile, 4 waves * 4x4 16x16x32 MFMAs.
// (No T2 swizzle here: measured NULL on 128^2 2-phase GEMM structures.)
__global__ __launch_bounds__(256) void gemm_qkv(
    const u16* __restrict__ cvt, u16* __restrict__ Qp,
    u16* __restrict__ Kp, u16* __restrict__ Vtp) {
  __shared__ u16 As[128 * 64];
  __shared__ u16 Bs[128 * 64];
  const int z = blockIdx.z;
  const u16* A = cvt + (size_t)z * QKVE;
  const u16* W = cvt + 3 * QKVE + (size_t)z * WEL;
  u16* dst = (z == 0) ? Qp : (z == 1) ? Kp : Vtp;
  const int K = Dx;
  const int tid = threadIdx.x;
  const int lane = tid & 63;
  const int l15 = lane & 15;
  const int quad = lane >> 4;
  const int wave = tid >> 6;
  const int m0 = blockIdx.y * 128;
  const int n0 = blockIdx.x * 128;
  const int wr = (wave >> 1) * 64;
  const int wc = (wave & 1) * 64;

  f32x4 acc[4][4];
#pragma unroll
  for (int i = 0; i < 4; i++)
#pragma unroll
    for (int j = 0; j < 4; j++) acc[i][j] = f32x4{0.f, 0.f, 0.f, 0.f};

  for (int k0 = 0; k0 < K; k0 += 64) {
    stage_lds_b16<128, 64, false>(A + (size_t)m0 * K + k0, K, As);
    stage_lds_b16<128, 64, false>(W + (size_t)n0 * K + k0, K, Bs);
    __syncthreads();
#pragma unroll
    for (int kk = 0; kk < 2; kk++) {
      bf16x8 af[4], bfv[4];
#pragma unroll
      for (int i = 0; i < 4; i++)
        af[i] = *(const bf16x8*)&As[(wr + i * 16 + l15) * 64 + kk * 32 + quad * 8];
#pragma unroll
      for (int j = 0; j < 4; j++)
        bfv[j] = *(const bf16x8*)&Bs[(wc + j * 16 + l15) * 64 + kk * 32 + quad * 8];
#pragma unroll
      for (int i = 0; i < 4; i++)
#pragma unroll
        for (int j = 0; j < 4; j++)
          acc[i][j] = __builtin_amdgcn_mfma_f32_16x16x32_bf16(af[i], bfv[j],
                                                              acc[i][j], 0, 0, 0);
    }
    __syncthreads();
  }

#pragma unroll
  for (int i = 0; i < 4; i++)
#pragma unroll
    for (int j = 0; j < 4; j++)
#pragma unroll
      for (int r = 0; r < 4; r++) {
        int row = m0 + wr + i * 16 + quad * 4 + r;  // token index
        int col = n0 + wc + j * 16 + l15;           // feature index
        float fv = acc[i][j][r];
        int b = row >> 11, t = row & 2047;
        int h = col >> 6, dk = col & 63;
        if (z != 2) {
          dst[(((size_t)(b * Hx + h) * Tx) + t) * DKx + dk] = f32_to_bf16(fv);
        } else {
          dst[(((size_t)(b * Hx + h) * DKx) + dk) * Tx + t] = f32_to_bf16(fv);
        }
      }
}

// Final output GEMM: A = comb (bf16 ws) via global_load_lds, B = Wo (f32,
// converted in-kernel), C = f32 row-major, nontemporal (never re-read).
__global__ __launch_bounds__(256) void gemm_out(
    const u16* __restrict__ Acomb, const float* __restrict__ Wo,
    float* __restrict__ out) {
  __shared__ u16 As[128 * 64];
  __shared__ u16 Bs[128 * 64];
  const int K = Dx, N = Dx;
  const int tid = threadIdx.x;
  const int lane = tid & 63;
  const int l15 = lane & 15;
  const int quad = lane >> 4;
  const int wave = tid >> 6;
  const int m0 = blockIdx.y * 128;
  const int n0 = blockIdx.x * 128;
  const int wr = (wave >> 1) * 64;
  const int wc = (wave & 1) * 64;

  f32x4 acc[4][4];
#pragma unroll
  for (int i = 0; i < 4; i++)
#pragma unroll
    for (int j = 0; j < 4; j++) acc[i][j] = f32x4{0.f, 0.f, 0.f, 0.f};

  for (int k0 = 0; k0 < K; k0 += 64) {
    stage_lds_b16<128, 64, false>(Acomb + (size_t)m0 * K + k0, K, As);
    stage_tile_f32<128, 64>(Wo + (size_t)n0 * K + k0, K, Bs);
    __syncthreads();
#pragma unroll
    for (int kk = 0; kk < 2; kk++) {
      bf16x8 af[4], bfv[4];
#pragma unroll
      for (int i = 0; i < 4; i++)
        af[i] = *(const bf16x8*)&As[(wr + i * 16 + l15) * 64 + kk * 32 + quad * 8];
#pragma unroll
      for (int j = 0; j < 4; j++)
        bfv[j] = *(const bf16x8*)&Bs[(wc + j * 16 + l15) * 64 + kk * 32 + quad * 8];
#pragma unroll
      for (int i = 0; i < 4; i++)
#pragma unroll
        for (int j = 0; j < 4; j++)
          acc[i][j] = __builtin_amdgcn_mfma_f32_16x16x32_bf16(af[i], bfv[j],
                                                              acc[i][j], 0, 0, 0);
    }
    __syncthreads();
  }

#pragma unroll
  for (int i = 0; i < 4; i++)
#pragma unroll
    for (int j = 0; j < 4; j++)
#pragma unroll
      for (int r = 0; r < 4; r++) {
        int row = m0 + wr + i * 16 + quad * 4 + r;
        int col = n0 + wc + j * 16 + l15;
        __builtin_nontemporal_store(acc[i][j][r], &out[(size_t)row * N + col]);
      }
}

// Attention: grid.x = T/64 (q blocks of 64), grid.y = B*H.
// 4 waves; each wave owns 16 q rows. Pass A: online softmax (m,l).
// Pass B: recompute S, write P (f32 attn weights, nontemporal) + O = P*V.
// All LDS tiles XOR-swizzled (T2): Ks/Vs via pre-swizzled global source,
// Ps symmetric write/read swizzle.
__global__ __launch_bounds__(256) void attn_kernel(
    const u16* __restrict__ Q,    // (B,H,T,DK) bf16 ws
    const u16* __restrict__ Kt,   // (B,H,T,DK) bf16 ws
    const u16* __restrict__ Vt,   // (B,H,DK,T) bf16 ws
    float* __restrict__ attnW,    // (B,H,T,T)  FLOAT32 out
    u16* __restrict__ comb) {     // (B,T,D)    bf16 ws
  __shared__ u16 Ks[128 * 64];
  __shared__ u16 Vs[64 * 128];
  __shared__ u16 Ps[4][16 * 128];

  const int tid = threadIdx.x, lane = tid & 63, wave = tid >> 6;
  const int l15 = lane & 15, quad = lane >> 4;
  const int bh = blockIdx.y;
  const int b = bh >> 4, h = bh & 15;
  const int q0 = blockIdx.x * 64;
  const u16* Qbh = Q + (size_t)bh * Tx * DKx;
  const u16* Kbh = Kt + (size_t)bh * Tx * DKx;
  const u16* Vbh = Vt + (size_t)bh * DKx * Tx;
  float* Wbh = attnW + (size_t)bh * Tx * Tx;

  // Q fragments for this wave's 16 rows (A-operand layout: m=l15, k=quad*8+j)
  bf16x8 qf[2];
  {
    const u16* qrow = Qbh + (size_t)(q0 + wave * 16 + l15) * DKx;
    qf[0] = *(const bf16x8*)(qrow + quad * 8);
    qf[1] = *(const bf16x8*)(qrow + 32 + quad * 8);
  }
  const int myrow_base = q0 + wave * 16;
  float m_r[4], l_r[4];
#pragma unroll
  for (int r = 0; r < 4; r++) { m_r[r] = -1e30f; l_r[r] = 0.0f; }

  const int ktmax = (q0 + 63) >> 7;  // inclusive: tiles with any visible col
  const float scale = 0.125f;        // 1/sqrt(64)

  // ---- Pass A: running max / denom ----
  for (int kt = 0; kt <= ktmax; kt++) {
    stage_lds_b16<128, 64, true>(Kbh + (size_t)kt * 128 * DKx, DKx, Ks);
    __syncthreads();
    f32x4 s[8];
#pragma unroll
    for (int j = 0; j < 8; j++) s[j] = f32x4{0.f, 0.f, 0.f, 0.f};
#pragma unroll
    for (int kk = 0; kk < 2; kk++)
#pragma unroll
      for (int j = 0; j < 8; j++) {
        int krow = j * 16 + l15;
        bf16x8 bfr = *(const bf16x8*)&Ks[(krow * 64 + kk * 32 + quad * 8) ^
                                         ((krow & 7) << 3)];
        s[j] = __builtin_amdgcn_mfma_f32_16x16x32_bf16(qf[kk], bfr, s[j], 0, 0, 0);
      }
#pragma unroll
    for (int r = 0; r < 4; r++) {
      int row = myrow_base + quad * 4 + r;
      float vals[8];
      float mx = -1e30f;
#pragma unroll
      for (int j = 0; j < 8; j++) {
        int col = kt * 128 + j * 16 + l15;
        float v = (col <= row) ? s[j][r] * scale : -1e30f;
        vals[j] = v;
        mx = fmaxf(mx, v);
      }
#pragma unroll
      for (int off = 1; off < 16; off <<= 1) mx = fmaxf(mx, __shfl_xor(mx, off));
      float mnew = fmaxf(m_r[r], mx);
      float sum = 0.0f;
#pragma unroll
      for (int j = 0; j < 8; j++) sum += __expf(vals[j] - mnew);
#pragma unroll
      for (int off = 1; off < 16; off <<= 1) sum += __shfl_xor(sum, off);
      l_r[r] = l_r[r] * __expf(m_r[r] - mnew) + sum;
      m_r[r] = mnew;
    }
    __syncthreads();
  }

  float il[4];
#pragma unroll
  for (int r = 0; r < 4; r++) il[r] = 1.0f / l_r[r];

  f32x4 o[4];
#pragma unroll
  for (int j = 0; j < 4; j++) o[j] = f32x4{0.f, 0.f, 0.f, 0.f};

  u16* Pw = Ps[wave];

  // ---- Pass B: P write (f32) + PV accumulate ----
  for (int kt = 0; kt < Tx / 128; kt++) {
    if (kt <= ktmax) {
      stage_lds_b16<128, 64, true>(Kbh + (size_t)kt * 128 * DKx, DKx, Ks);
      stage_lds_b16<64, 128, true>(Vbh + (size_t)kt * 128, Tx, Vs);
      __syncthreads();
      f32x4 s[8];
#pragma unroll
      for (int j = 0; j < 8; j++) s[j] = f32x4{0.f, 0.f, 0.f, 0.f};
#pragma unroll
      for (int kk = 0; kk < 2; kk++)
#pragma unroll
        for (int j = 0; j < 8; j++) {
          int krow = j * 16 + l15;
          bf16x8 bfr = *(const bf16x8*)&Ks[(krow * 64 + kk * 32 + quad * 8) ^
                                           ((krow & 7) << 3)];
          s[j] = __builtin_amdgcn_mfma_f32_16x16x32_bf16(qf[kk], bfr, s[j], 0, 0, 0);
        }
      // P = exp(s - m)/l: f32 -> global (nontemporal; 537 MB stream),
      // bf16 -> LDS (A-layout transform for the PV MFMA; swizzled write)
#pragma unroll
      for (int j = 0; j < 8; j++)
#pragma unroll
        for (int r = 0; r < 4; r++) {
          int row = myrow_base + quad * 4 + r;
          int col = kt * 128 + j * 16 + l15;
          float p = (col <= row) ? __expf(s[j][r] * scale - m_r[r]) * il[r] : 0.0f;
          int prow = quad * 4 + r;
          Pw[(prow * 128 + j * 16 + l15) ^ ((prow & 15) << 3)] = f32_to_bf16(p);
          __builtin_nontemporal_store(p, &Wbh[(size_t)row * Tx + col]);
        }
      // O += P * V
#pragma unroll
      for (int kk = 0; kk < 4; kk++) {
        bf16x8 af = *(const bf16x8*)&Pw[(l15 * 128 + kk * 32 + quad * 8) ^
                                        ((l15 & 15) << 3)];
#pragma unroll
        for (int j = 0; j < 4; j++) {
          int vrow = j * 16 + l15;
          bf16x8 bfr = *(const bf16x8*)&Vs[(vrow * 128 + kk * 32 + quad * 8) ^
                                           ((vrow & 15) << 3)];
          o[j] = __builtin_amdgcn_mfma_f32_16x16x32_bf16(af, bfr, o[j], 0, 0, 0);
        }
      }
      __syncthreads();
    } else {
      // fully masked tile: f32 zeros (16 rows x 128 cols), ext-vector
      // nontemporal stores (HIP float4 class is rejected by the builtin)
      f32x4 z = {0.f, 0.f, 0.f, 0.f};
#pragma unroll
      for (int i = 0; i < 8; i++) {
        int c = i * 64 + lane;          // 0..511
        int pr = c >> 5, pc = c & 31;   // row 0..15, float4 chunk 0..31
        __builtin_nontemporal_store(
            z, (f32x4*)&Wbh[(size_t)(myrow_base + pr) * Tx + kt * 128 + pc * 4]);
      }
    }
  }

  // write O into combined (B,T,D) bf16 ws layout
#pragma unroll
  for (int j = 0; j < 4; j++)
#pragma unroll
    for (int r = 0; r < 4; r++) {
      int row = myrow_base + quad * 4 + r;   // t
      int dk = j * 16 + l15;
      comb[((size_t)b * Tx + row) * Dx + h * 64 + dk] = f32_to_bf16(o[j][r]);
    }
}

extern "C" void kernel_launch(void* const* d_in, const int* in_sizes, int n_in,
                              void* d_out, int out_size, void* d_ws, size_t ws_size,
                              hipStream_t stream) {
  // Inputs AND outputs are FLOAT32 per the reference.
  const float* q  = (const float*)d_in[0];
  const float* k  = (const float*)d_in[1];
  const float* v  = (const float*)d_in[2];
  // d_in[3] = causal mask -- deterministic triu(k=1), recomputed in-kernel
  const float* Wq = (const float*)d_in[4];
  const float* Wk = (const float*)d_in[5];
  const float* Wv = (const float*)d_in[6];
  const float* Wo = (const float*)d_in[7];

  float* out  = (float*)d_out;                    // (B,T,D) f32
  float* attn = out + QKVE;                       // (B,H,T,T) f32

  u16* ws = (u16*)d_ws;
  const size_t QKV = QKVE;                        // 4,194,304 elems
  u16* Qp   = ws;
  u16* Kp   = ws + QKV;
  u16* Vtp  = ws + 2 * QKV;
  u16* comb = ws + 3 * QKV;

  // bf16 staging scratch lives in the attnW output region: it is dead until
  // attn_kernel overwrites every element of attnW (ws footprint unchanged).
  u16* cvt = (u16*)attn;  // 3*QKVE + 3*WEL u16 = 33.6 MB << 537 MB

  dim3 blk(256);
  cvt_kernel<<<dim3(1024), blk, 0, stream>>>(q, k, v, Wq, Wk, Wv, cvt);

  dim3 g1(Dx / 128, (Bx * Tx) / 128, 3);  // (8, 32, 3) = 768 blocks
  gemm_qkv<<<g1, blk, 0, stream>>>(cvt, Qp, Kp, Vtp);

  dim3 g2(Tx / 64, Bx * Hx);  // (32, 32)
  attn_kernel<<<g2, blk, 0, stream>>>(Qp, Kp, Vtp, attn, comb);

  dim3 g3(Dx / 128, (Bx * Tx) / 128);  // (8, 32)
  gemm_out<<<g3, blk, 0, stream>>>(comb, Wo, out);
}